// Round 1
// baseline (111044.727 us; speedup 1.0000x reference)
//
#include <hip/hip_runtime.h>
#include <math.h>

// Problem constants
#define B   64
#define T   512
#define D   1024
#define H   1024
#define E   128
#define O   512

#define NBLK 256
#define NTHR 256

// ws byte layout
//   0        : hbuf[2][64][1024] float  (524288 B)
//   524288   : amax[2][64] u64          (1024 B)
//   525440   : gen  (u32)
//   525568   : cnt0 (u32)
//   525696   : cnt1 (u32)

__global__ __launch_bounds__(NTHR) void init_kernel(float* hbuf0, unsigned* gen,
                                                    unsigned* cnt0, unsigned* cnt1) {
  int i = blockIdx.x * NTHR + threadIdx.x;
  if (i < B * H) hbuf0[i] = 0.f;          // zero h buffer 0 (t=0 reads it)
  if (i == 0) { *gen = 0u; *cnt0 = 0u; *cnt1 = 0u; }
}

// Device-wide barrier: 256 blocks, sense via generation counter, ping-pong
// arrival counters (slot q&1). AGENT-scope atomics handle cross-XCD coherence:
// release on arrive (flush L2), acquire on spin (invalidate), so plain global
// data written before the barrier is visible after it.
__device__ __forceinline__ void gbar(unsigned* cnt0, unsigned* cnt1, unsigned* gen,
                                     unsigned q) {
  __syncthreads();
  if (threadIdx.x == 0) {
    unsigned* c = (q & 1u) ? cnt1 : cnt0;
    __threadfence();  // agent release fence (belt & braces w/ acq_rel below)
    unsigned arrived = __hip_atomic_fetch_add(c, 1u, __ATOMIC_ACQ_REL,
                                              __HIP_MEMORY_SCOPE_AGENT);
    if (arrived == NBLK - 1u) {
      __hip_atomic_store(c, 0u, __ATOMIC_RELAXED, __HIP_MEMORY_SCOPE_AGENT);
      __hip_atomic_store(gen, q + 1u, __ATOMIC_RELEASE, __HIP_MEMORY_SCOPE_AGENT);
    } else {
      while (__hip_atomic_load(gen, __ATOMIC_ACQUIRE, __HIP_MEMORY_SCOPE_AGENT) < q + 1u) {
        __builtin_amdgcn_s_sleep(1);
      }
    }
  }
  __syncthreads();
}

__device__ __forceinline__ float sigm(float x) { return 1.f / (1.f + expf(-x)); }

__global__ __launch_bounds__(NTHR) void decode_kernel(
    const float* __restrict__ enc, const int* __restrict__ seq_lens,
    const float* __restrict__ W_ih, const float* __restrict__ W_hh,
    const float* __restrict__ b_ih, const float* __restrict__ b_hh,
    const float* __restrict__ W_lin, const float* __restrict__ b_lin,
    const float* __restrict__ emb, const float* __restrict__ init_t,
    float* __restrict__ out, float* __restrict__ hbuf,
    unsigned long long* __restrict__ amax,
    unsigned* gen, unsigned* cnt0, unsigned* cnt1) {

  const int tid  = threadIdx.x;
  const int lane = tid & 63;
  const int wv   = tid >> 6;
  const int bid  = blockIdx.x;

  // LDS: z-slab [64 rows][132 floats] (stride 132: 16B-aligned rows, banks balanced
  // for b128), per-batch feedback index, logit stash for coalesced store.
  __shared__ float zt[64 * 132];
  __shared__ int   idxbuf[64];
  __shared__ float lstash[128];

  // ---- phase A identity: wave -> hidden index m, lane -> batch b ----
  const int m = __builtin_amdgcn_readfirstlane(bid * 4 + wv);  // 0..1023, wave-uniform
  const int b = lane;
  const int sl = seq_lens[b];

  // ---- phase B identity: block -> (batch, o-tile) ----
  const int b_pb  = bid >> 2;
  const int otile = bid & 3;
  const int slB   = seq_lens[b_pb];

  // Wave-uniform weight row pointers (gate order i,f,g,o = rows m, H+m, 2H+m, 3H+m)
  const float* Wi0 = W_ih + (size_t)(0 * H + m) * (D + E);
  const float* Wi1 = W_ih + (size_t)(1 * H + m) * (D + E);
  const float* Wi2 = W_ih + (size_t)(2 * H + m) * (D + E);
  const float* Wi3 = W_ih + (size_t)(3 * H + m) * (D + E);
  const float* Wh0 = W_hh + (size_t)(0 * H + m) * H;
  const float* Wh1 = W_hh + (size_t)(1 * H + m) * H;
  const float* Wh2 = W_hh + (size_t)(2 * H + m) * H;
  const float* Wh3 = W_hh + (size_t)(3 * H + m) * H;
  const float bias0 = b_ih[0 * H + m] + b_hh[0 * H + m];
  const float bias1 = b_ih[1 * H + m] + b_hh[1 * H + m];
  const float bias2 = b_ih[2 * H + m] + b_hh[2 * H + m];
  const float bias3 = b_ih[3 * H + m] + b_hh[3 * H + m];

  float c_reg = 0.f;   // cell state, owned by (b, m) thread across all steps
  float h_reg = 0.f;   // committed hidden state for (b, m)

  if (tid < 64) idxbuf[tid] = -1;  // -1 => use init_tensor as prev_emb

  for (int t = 0; t < T; ++t) {
    // ---------- A-pre: feedback index update + amax[t&1] reset ----------
    if (tid < 64) {
      if (t > 0 && (t - 1) < seq_lens[tid]) {
        unsigned long long p = __hip_atomic_load(
            &amax[((t - 1) & 1) * 64 + tid], __ATOMIC_RELAXED, __HIP_MEMORY_SCOPE_AGENT);
        idxbuf[tid] = 511 - (int)(unsigned)(p & 0xffffffffu);
      }
    } else if (tid < 128) {
      __hip_atomic_store(&amax[(t & 1) * 64 + (tid - 64)], 0ull,
                         __ATOMIC_RELAXED, __HIP_MEMORY_SCOPE_AGENT);
    }
    __syncthreads();

    float g0 = bias0, g1 = bias1, g2 = bias2, g3 = bias3;
    const float* hprev = hbuf + (size_t)(t & 1) * (B * H);

    // ---------- phase A: gates = [x|h|emb] . W rows, K chunked by 128 ----------
    for (int ch = 0; ch < 17; ++ch) {
      {  // stage chunk: 64 rows x 128 floats, coalesced float4
        const int ks = (tid & 31) * 4;
        int bs = tid >> 5;  // 0..7, advance by 8
        for (int r = 0; r < 8; ++r, bs += 8) {
          float4 v;
          if (ch < 8) {
            v = *(const float4*)(enc + ((size_t)bs * T + t) * D + ch * 128 + ks);
          } else if (ch < 16) {
            v = *(const float4*)(hprev + (size_t)bs * H + (ch - 8) * 128 + ks);
          } else {
            const int idx = idxbuf[bs];
            const float* src = (idx < 0) ? (init_t + ks) : (emb + (size_t)idx * E + ks);
            v = *(const float4*)src;
          }
          *(float4*)(&zt[bs * 132 + ks]) = v;
        }
      }
      __syncthreads();

      const float *r0, *r1, *r2, *r3;
      if (ch < 8)       { const int off = ch * 128;       r0 = Wi0 + off; r1 = Wi1 + off; r2 = Wi2 + off; r3 = Wi3 + off; }
      else if (ch < 16) { const int off = (ch - 8) * 128; r0 = Wh0 + off; r1 = Wh1 + off; r2 = Wh2 + off; r3 = Wh3 + off; }
      else              {                                 r0 = Wi0 + D;   r1 = Wi1 + D;   r2 = Wi2 + D;   r3 = Wi3 + D;   }

      const float* zrow = &zt[b * 132];
      #pragma unroll 8
      for (int k = 0; k < 128; k += 4) {
        float4 z4 = *(const float4*)(zrow + k);
        g0 = fmaf(r0[k + 0], z4.x, g0); g1 = fmaf(r1[k + 0], z4.x, g1);
        g2 = fmaf(r2[k + 0], z4.x, g2); g3 = fmaf(r3[k + 0], z4.x, g3);
        g0 = fmaf(r0[k + 1], z4.y, g0); g1 = fmaf(r1[k + 1], z4.y, g1);
        g2 = fmaf(r2[k + 1], z4.y, g2); g3 = fmaf(r3[k + 1], z4.y, g3);
        g0 = fmaf(r0[k + 2], z4.z, g0); g1 = fmaf(r1[k + 2], z4.z, g1);
        g2 = fmaf(r2[k + 2], z4.z, g2); g3 = fmaf(r3[k + 2], z4.z, g3);
        g0 = fmaf(r0[k + 3], z4.w, g0); g1 = fmaf(r1[k + 3], z4.w, g1);
        g2 = fmaf(r2[k + 3], z4.w, g2); g3 = fmaf(r3[k + 3], z4.w, g3);
      }
      __syncthreads();
    }

    // ---------- LSTM cell (torch gate order i,f,g,o) ----------
    {
      const float xi = sigm(g0);
      const float xf = sigm(g1);
      const float xg = tanhf(g2);
      const float xo = sigm(g3);
      const float cn = xf * c_reg + xi * xg;
      const float hn = xo * tanhf(cn);
      if (t < sl) { c_reg = cn; h_reg = hn; }  // masked commit
      hbuf[(size_t)((t + 1) & 1) * (B * H) + (size_t)b * H + m] = h_reg;
    }

    gbar(cnt0, cnt1, gen, 2u * (unsigned)t);  // h_t complete device-wide

    // ---------- phase B: logits, argmax, output ----------
    {  // stage h row for this block's batch
      float4 v = *(const float4*)(hbuf + (size_t)((t + 1) & 1) * (B * H) +
                                  (size_t)b_pb * H + tid * 4);
      *(float4*)(&zt[tid * 4]) = v;
    }
    __syncthreads();

    unsigned long long best = 0ull;
    const int obase = otile * 128 + wv * 32;
    for (int oi = 0; oi < 32; ++oi) {
      const int o = obase + oi;
      const float* Wr = W_lin + (size_t)o * H;
      const int kb = lane * 16;
      float acc = 0.f;
      #pragma unroll
      for (int j = 0; j < 4; ++j) {
        float4 w4 = *(const float4*)(Wr + kb + j * 4);
        float4 h4 = *(const float4*)(&zt[kb + j * 4]);
        acc += w4.x * h4.x + w4.y * h4.y + w4.z * h4.z + w4.w * h4.w;
      }
      for (int s = 32; s > 0; s >>= 1) acc += __shfl_xor(acc, s, 64);
      const float logit = acc + b_lin[o];
      if (lane == 0) lstash[wv * 32 + oi] = logit;
      // packed argmax key: ordered-float in high bits, (511-o) low => numpy
      // first-index tie-break under max.
      unsigned kbits = __float_as_uint(logit);
      kbits = (kbits & 0x80000000u) ? ~kbits : (kbits | 0x80000000u);
      unsigned long long pk =
          ((unsigned long long)kbits << 32) | (unsigned long long)(511 - o);
      best = best > pk ? best : pk;
    }
    if (lane == 0) atomicMax(&amax[(t & 1) * 64 + b_pb], best);
    __syncthreads();
    if (tid < 128) {
      const float v = (t < slB) ? lstash[tid] : 0.f;
      out[((size_t)b_pb * T + t) * O + otile * 128 + tid] = v;
    }

    gbar(cnt0, cnt1, gen, 2u * (unsigned)t + 1u);  // logits/argmax complete
  }
}

extern "C" void kernel_launch(void* const* d_in, const int* in_sizes, int n_in,
                              void* d_out, int out_size, void* d_ws, size_t ws_size,
                              hipStream_t stream) {
  (void)in_sizes; (void)n_in; (void)out_size; (void)ws_size;
  const float* enc    = (const float*)d_in[0];
  const int*   slen   = (const int*)d_in[1];
  const float* W_ih   = (const float*)d_in[2];
  const float* W_hh   = (const float*)d_in[3];
  const float* b_ih   = (const float*)d_in[4];
  const float* b_hh   = (const float*)d_in[5];
  const float* W_lin  = (const float*)d_in[6];
  const float* b_lin  = (const float*)d_in[7];
  const float* emb    = (const float*)d_in[8];
  const float* init_t = (const float*)d_in[9];
  float* out = (float*)d_out;

  char* ws = (char*)d_ws;
  float* hbuf = (float*)ws;                                       // 524288 B
  unsigned long long* amax = (unsigned long long*)(ws + 524288);  // 1024 B
  unsigned* gen  = (unsigned*)(ws + 525440);
  unsigned* cnt0 = (unsigned*)(ws + 525568);
  unsigned* cnt1 = (unsigned*)(ws + 525696);

  hipLaunchKernelGGL(init_kernel, dim3(NBLK), dim3(NTHR), 0, stream,
                     hbuf, gen, cnt0, cnt1);
  hipLaunchKernelGGL(decode_kernel, dim3(NBLK), dim3(NTHR), 0, stream,
                     enc, slen, W_ih, W_hh, b_ih, b_hh, W_lin, b_lin, emb,
                     init_t, out, hbuf, amax, gen, cnt0, cnt1);
}

// Round 2
// 50719.061 us; speedup vs baseline: 2.1894x; 2.1894x over previous
//
#include <hip/hip_runtime.h>
#include <math.h>

// Problem constants
#define B    64
#define T    512
#define D    1024
#define H    1024
#define E    128
#define OO   512

#define NBLK 256
#define NTHR 512

// Dynamic LDS layout (bytes):
//   wslab : 16 rows x 2176 fp32 = 139264   (block's 16 gate-rows, resident all steps)
//   kbuf  : 64 u64               =    512   (argmax partials, 8 waves x 8 b)
//   gbuf  : 16 x 68 fp32         =   4352   (gate accumulators, padded stride 68)
//   bias16: 16 fp32              =     64
//   lstash: 8 x 17 fp32          =    544   (logit stash, padded)
//   idxbuf: 64 int               =    256   (greedy feedback indices)
#define SMEM_BYTES 145024

// ws byte layout
//   0        : hbuf[2][64][1024] float  (524288 B)
//   524288   : amax[2][64] u64          (1024 B)
//   525440   : gen  (u32)
//   525568   : cnt0 (u32)
//   525696   : cnt1 (u32)

__global__ __launch_bounds__(256) void init_kernel(float* hbuf0, unsigned* gen,
                                                   unsigned* cnt0, unsigned* cnt1) {
  int i = blockIdx.x * 256 + threadIdx.x;
  if (i < B * H) hbuf0[i] = 0.f;  // zero h buffer 0 (t=0 reads it)
  if (i == 0) { *gen = 0u; *cnt0 = 0u; *cnt1 = 0u; }
}

// Device-wide barrier (proven in round 1): sense via generation counter,
// ping-pong arrival counters. AGENT-scope atomics give cross-XCD release/
// acquire so plain global data written before is visible after.
__device__ __forceinline__ void gbar(unsigned* cnt0, unsigned* cnt1, unsigned* gen,
                                     unsigned q) {
  __syncthreads();
  if (threadIdx.x == 0) {
    unsigned* c = (q & 1u) ? cnt1 : cnt0;
    __threadfence();
    unsigned arrived = __hip_atomic_fetch_add(c, 1u, __ATOMIC_ACQ_REL,
                                              __HIP_MEMORY_SCOPE_AGENT);
    if (arrived == NBLK - 1u) {
      __hip_atomic_store(c, 0u, __ATOMIC_RELAXED, __HIP_MEMORY_SCOPE_AGENT);
      __hip_atomic_store(gen, q + 1u, __ATOMIC_RELEASE, __HIP_MEMORY_SCOPE_AGENT);
    } else {
      while (__hip_atomic_load(gen, __ATOMIC_ACQUIRE, __HIP_MEMORY_SCOPE_AGENT) < q + 1u) {
        __builtin_amdgcn_s_sleep(1);
      }
    }
  }
  __syncthreads();
}

__device__ __forceinline__ float sigm(float x) { return 1.f / (1.f + expf(-x)); }

// 4 consecutive-k FMAs of one LDS weight row against a z float4
#define ROWFMA(r, wp, z4)                                        \
  {                                                              \
    float4 w4 = *(const float4*)((wp) + (r) * 2176);             \
    acc[r] = fmaf(w4.x, (z4).x, acc[r]);                         \
    acc[r] = fmaf(w4.y, (z4).y, acc[r]);                         \
    acc[r] = fmaf(w4.z, (z4).z, acc[r]);                         \
    acc[r] = fmaf(w4.w, (z4).w, acc[r]);                         \
  }

#define ALLROWS(wp, z4)                                          \
  ROWFMA(0, wp, z4)  ROWFMA(1, wp, z4)  ROWFMA(2, wp, z4)        \
  ROWFMA(3, wp, z4)  ROWFMA(4, wp, z4)  ROWFMA(5, wp, z4)        \
  ROWFMA(6, wp, z4)  ROWFMA(7, wp, z4)  ROWFMA(8, wp, z4)        \
  ROWFMA(9, wp, z4)  ROWFMA(10, wp, z4) ROWFMA(11, wp, z4)       \
  ROWFMA(12, wp, z4) ROWFMA(13, wp, z4) ROWFMA(14, wp, z4)       \
  ROWFMA(15, wp, z4)

__global__ __launch_bounds__(NTHR, 2) void decode_kernel(
    const float* __restrict__ enc, const int* __restrict__ seq_lens,
    const float* __restrict__ W_ih, const float* __restrict__ W_hh,
    const float* __restrict__ b_ih, const float* __restrict__ b_hh,
    const float* __restrict__ W_lin, const float* __restrict__ b_lin,
    const float* __restrict__ emb, const float* __restrict__ init_t,
    float* __restrict__ out, float* __restrict__ hbuf,
    unsigned long long* __restrict__ amax,
    unsigned* gen, unsigned* cnt0, unsigned* cnt1) {

  extern __shared__ char smem_raw[];
  float* wslab = (float*)smem_raw;                                  // 34816 f
  unsigned long long* kbuf = (unsigned long long*)(smem_raw + 139264);  // 64 u64
  float* gbuf   = (float*)(smem_raw + 139776);                      // 1088 f
  float* bias16 = gbuf + 1088;                                      // 16 f
  float* lstash = bias16 + 16;                                      // 136 f
  int*   idxbuf = (int*)(lstash + 136);                             // 64 i

  const int tid  = threadIdx.x;
  const int lane = tid & 63;
  const int wv   = tid >> 6;          // 0..7
  const int bid  = blockIdx.x;

  // ---------- prologue: load this block's 16 gate-rows into LDS ----------
  // row slot s = g*4 + mi  <->  global row r = g*H + (bid*4 + mi)
  // packed row layout: [W_ih[r][0:1024] | W_hh[r][0:1024] | W_ih[r][1024:1152]]
  for (int idx = tid; idx < 16 * 544; idx += NTHR) {
    const int s = idx / 544, j = idx - s * 544;  // j in float4 units
    const int g = s >> 2, mi = s & 3;
    const int r = g * H + (bid * 4 + mi);
    float4 v;
    if (j < 256)      v = *(const float4*)(W_ih + (size_t)r * (D + E) + j * 4);
    else if (j < 512) v = *(const float4*)(W_hh + (size_t)r * H + (j - 256) * 4);
    else              v = *(const float4*)(W_ih + (size_t)r * (D + E) + D + (j - 512) * 4);
    *(float4*)(wslab + s * 2176 + j * 4) = v;
  }
  if (tid < 16) {
    const int g = tid >> 2, mi = tid & 3;
    const int r = g * H + (bid * 4 + mi);
    bias16[tid] = b_ih[r] + b_hh[r];
  }
  if (tid < 64) idxbuf[tid] = -1;  // -1 => init_tensor as prev_emb

  // ---------- identities ----------
  // phase A: wave = b-octet, lane = (b low 3 bits -> kp split of K)
  const int za_b = wv * 8 + (lane >> 3);  // batch this lane accumulates for
  const int kp   = lane & 7;              // k-interleave slot (float4 granular)
  // cell update: tid<256 owns (mi, b) state
  const int cb  = tid & 63;
  const int cmi = tid >> 6;               // valid when tid < 256
  const int csl = seq_lens[cb];
  const int sl_pre = (tid < 64) ? seq_lens[tid] : 0;
  // phase B: block = (bq: 8 batches, og: 16 outputs)
  const int bq = bid >> 5, og = bid & 31;
  const int pb_b  = bq * 8 + (lane >> 3);
  const int pb_sl = seq_lens[pb_b];
  const int o0 = og * 16 + wv * 2, o1 = o0 + 1;
  const float bl0 = b_lin[o0], bl1 = b_lin[o1];

  float c_reg = 0.f, h_reg = 0.f;  // LSTM state, owned by tid<256 threads

  __syncthreads();

  for (int t = 0; t < T; ++t) {
    // ---------- A-pre: feedback index + amax slot reset ----------
    if (tid < 64) {
      if (t > 0 && (t - 1) < sl_pre) {
        unsigned long long p = __hip_atomic_load(
            &amax[((t - 1) & 1) * 64 + tid], __ATOMIC_RELAXED, __HIP_MEMORY_SCOPE_AGENT);
        idxbuf[tid] = 511 - (int)(unsigned)(p & 0xffffffffu);
      }
    } else if (tid < 128) {
      __hip_atomic_store(&amax[(t & 1) * 64 + (tid - 64)], 0ull,
                         __ATOMIC_RELAXED, __HIP_MEMORY_SCOPE_AGENT);
    }
    __syncthreads();

    // ---------- phase A: 16 gate-rows x (this lane's k-slice) ----------
    float acc[16];
    #pragma unroll
    for (int r = 0; r < 16; ++r) acc[r] = 0.f;

    const int eidx = idxbuf[za_b];
    const float* xs = enc + ((size_t)za_b * T + t) * D + kp * 4;
    const float* hs = hbuf + (size_t)(t & 1) * (B * H) + (size_t)za_b * H + kp * 4;
    const float* es = ((eidx < 0) ? init_t : (emb + (size_t)eidx * E)) + kp * 4;

    #pragma unroll 4
    for (int i = 0; i < 32; ++i) {           // x region (K 0..1023)
      float4 z4 = *(const float4*)(xs + i * 32);
      const float* wp = wslab + i * 32 + kp * 4;
      ALLROWS(wp, z4)
    }
    #pragma unroll 4
    for (int i = 0; i < 32; ++i) {           // h region (K 1024..2047)
      float4 z4 = *(const float4*)(hs + i * 32);
      const float* wp = wslab + 1024 + i * 32 + kp * 4;
      ALLROWS(wp, z4)
    }
    #pragma unroll
    for (int i = 0; i < 4; ++i) {            // emb region (K 2048..2175)
      float4 z4 = *(const float4*)(es + i * 32);
      const float* wp = wslab + 2048 + i * 32 + kp * 4;
      ALLROWS(wp, z4)
    }

    // butterfly-reduce the 8-way k split (kp lives in lane bits 0..2)
    #pragma unroll
    for (int r = 0; r < 16; ++r) {
      acc[r] += __shfl_xor(acc[r], 1, 64);
      acc[r] += __shfl_xor(acc[r], 2, 64);
      acc[r] += __shfl_xor(acc[r], 4, 64);
    }
    // every lane now has all 16 sums for its b; lane kp writes rows 2kp,2kp+1
    gbuf[(2 * kp) * 68 + za_b]     = acc[2 * kp];
    gbuf[(2 * kp + 1) * 68 + za_b] = acc[2 * kp + 1];
    __syncthreads();

    // ---------- LSTM cell (torch gate order i,f,g,o) ----------
    if (tid < 256) {
      const float gi = gbuf[(0 * 4 + cmi) * 68 + cb] + bias16[0 * 4 + cmi];
      const float gf = gbuf[(1 * 4 + cmi) * 68 + cb] + bias16[1 * 4 + cmi];
      const float gg = gbuf[(2 * 4 + cmi) * 68 + cb] + bias16[2 * 4 + cmi];
      const float go = gbuf[(3 * 4 + cmi) * 68 + cb] + bias16[3 * 4 + cmi];
      const float xi = sigm(gi), xf = sigm(gf), xg = tanhf(gg), xo = sigm(go);
      const float cn = xf * c_reg + xi * xg;
      const float hn = xo * tanhf(cn);
      if (t < csl) { c_reg = cn; h_reg = hn; }
      hbuf[(size_t)((t + 1) & 1) * (B * H) + (size_t)cb * H + (bid * 4 + cmi)] = h_reg;
    }

    gbar(cnt0, cnt1, gen, 2u * (unsigned)t);  // h_t complete device-wide

    // ---------- phase B: 2 logits per wave, kp-split over K ----------
    float f0 = 0.f, f1 = 0.f;
    const float* hr  = hbuf + (size_t)((t + 1) & 1) * (B * H) + (size_t)pb_b * H + kp * 4;
    const float* wl0 = W_lin + (size_t)o0 * H + kp * 4;
    const float* wl1 = W_lin + (size_t)o1 * H + kp * 4;
    #pragma unroll 4
    for (int j = 0; j < 32; ++j) {
      float4 h4 = *(const float4*)(hr + j * 32);
      float4 a4 = *(const float4*)(wl0 + j * 32);
      float4 c4 = *(const float4*)(wl1 + j * 32);
      f0 = fmaf(a4.x, h4.x, f0); f0 = fmaf(a4.y, h4.y, f0);
      f0 = fmaf(a4.z, h4.z, f0); f0 = fmaf(a4.w, h4.w, f0);
      f1 = fmaf(c4.x, h4.x, f1); f1 = fmaf(c4.y, h4.y, f1);
      f1 = fmaf(c4.z, h4.z, f1); f1 = fmaf(c4.w, h4.w, f1);
    }
    f0 += __shfl_xor(f0, 1, 64); f0 += __shfl_xor(f0, 2, 64); f0 += __shfl_xor(f0, 4, 64);
    f1 += __shfl_xor(f1, 1, 64); f1 += __shfl_xor(f1, 2, 64); f1 += __shfl_xor(f1, 4, 64);
    const float l0 = f0 + bl0, l1 = f1 + bl1;

    if (kp == 0) {
      const int boo = lane >> 3;
      const float s0 = (t < pb_sl) ? l0 : 0.f;
      const float s1 = (t < pb_sl) ? l1 : 0.f;
      lstash[boo * 17 + wv * 2]     = s0;
      lstash[boo * 17 + wv * 2 + 1] = s1;
      // packed argmax keys: ordered-float high, (511-o) low => first-index ties
      unsigned k0 = __float_as_uint(l0);
      k0 = (k0 & 0x80000000u) ? ~k0 : (k0 | 0x80000000u);
      unsigned k1 = __float_as_uint(l1);
      k1 = (k1 & 0x80000000u) ? ~k1 : (k1 | 0x80000000u);
      unsigned long long p0 = ((unsigned long long)k0 << 32) | (unsigned long long)(511 - o0);
      unsigned long long p1 = ((unsigned long long)k1 << 32) | (unsigned long long)(511 - o1);
      kbuf[wv * 8 + boo] = (p0 > p1) ? p0 : p1;
    }
    __syncthreads();
    if (tid < 8) {
      unsigned long long m = kbuf[tid];
      #pragma unroll
      for (int w = 1; w < 8; ++w) {
        unsigned long long v = kbuf[w * 8 + tid];
        m = (v > m) ? v : m;
      }
      atomicMax(&amax[(t & 1) * 64 + bq * 8 + tid], m);
    }
    if (tid < 128) {
      const int bb = tid >> 4, oj = tid & 15;
      out[((size_t)(bq * 8 + bb) * T + t) * OO + og * 16 + oj] = lstash[bb * 17 + oj];
    }

    gbar(cnt0, cnt1, gen, 2u * (unsigned)t + 1u);  // logits/argmax complete
  }
}

extern "C" void kernel_launch(void* const* d_in, const int* in_sizes, int n_in,
                              void* d_out, int out_size, void* d_ws, size_t ws_size,
                              hipStream_t stream) {
  (void)in_sizes; (void)n_in; (void)out_size; (void)ws_size;
  const float* enc    = (const float*)d_in[0];
  const int*   slen   = (const int*)d_in[1];
  const float* W_ih   = (const float*)d_in[2];
  const float* W_hh   = (const float*)d_in[3];
  const float* b_ih   = (const float*)d_in[4];
  const float* b_hh   = (const float*)d_in[5];
  const float* W_lin  = (const float*)d_in[6];
  const float* b_lin  = (const float*)d_in[7];
  const float* emb    = (const float*)d_in[8];
  const float* init_t = (const float*)d_in[9];
  float* out = (float*)d_out;

  char* ws = (char*)d_ws;
  float* hbuf = (float*)ws;                                       // 524288 B
  unsigned long long* amax = (unsigned long long*)(ws + 524288);  // 1024 B
  unsigned* gen  = (unsigned*)(ws + 525440);
  unsigned* cnt0 = (unsigned*)(ws + 525568);
  unsigned* cnt1 = (unsigned*)(ws + 525696);

  // 145 KB dynamic LDS (> 64 KB default) — gfx950 GROUP pool is 160 KiB/CU
  hipFuncSetAttribute((const void*)decode_kernel,
                      hipFuncAttributeMaxDynamicSharedMemorySize, SMEM_BYTES);

  hipLaunchKernelGGL(init_kernel, dim3(NBLK), dim3(256), 0, stream,
                     hbuf, gen, cnt0, cnt1);
  hipLaunchKernelGGL(decode_kernel, dim3(NBLK), dim3(NTHR), SMEM_BYTES, stream,
                     enc, slen, W_ih, W_hh, b_ih, b_hh, W_lin, b_lin, emb,
                     init_t, out, hbuf, amax, gen, cnt0, cnt1);
}

// Round 3
// 37109.265 us; speedup vs baseline: 2.9924x; 1.3667x over previous
//
#include <hip/hip_runtime.h>
#include <math.h>

// Problem constants
#define B    64
#define T    512
#define D    1024
#define H    1024
#define E    128
#define OO   512

#define NBLK 256
#define NTHR 512

typedef _Float16 f16x8 __attribute__((ext_vector_type(8)));
typedef float    f32x4 __attribute__((ext_vector_type(4)));

// All MFMA inputs are scaled by 128 (f16 denormal floor dodge); gates get
// scaled back by 1/(128*128) at the cell update. Exact pow2 => no rounding.
#define SCALE      128.0f
#define INV_SCALE2 (1.0f / 16384.0f)

// ws byte layout (all 16B-aligned)
#define WS_HBUF   0          // fp32 [2][64][1024]   = 524288 B
#define WS_H16HI  524288     // f16  [2][64][1024]   = 262144 B (scaled x128)
#define WS_H16LO  786432     // f16  [2][64][1024]   = 262144 B
#define WS_E16HI  1048576    // f16  [513][128]      = 131328 B (row 512 = init_tensor)
#define WS_E16LO  1179904    // f16  [513][128]      = 131328 B
#define WS_AMAX   1311232    // u64  [2][64]         = 1024 B
#define WS_GEN    1312384
#define WS_CNT0   1312512
#define WS_CNT1   1312640

__global__ __launch_bounds__(256) void init_kernel(
    float* hbuf0, _Float16* h16hi, _Float16* h16lo,
    _Float16* e16hi, _Float16* e16lo,
    const float* emb, const float* init_t,
    unsigned* gen, unsigned* cnt0, unsigned* cnt1) {
  const int i = blockIdx.x * 256 + threadIdx.x;  // 512 blocks -> 0..131071
  if (i < B * H) hbuf0[i] = 0.f;                 // h fp32 parity 0
  if (i < 2 * B * H) { h16hi[i] = (_Float16)0.f; h16lo[i] = (_Float16)0.f; }
  if (i < 513 * 128) {
    const int row = i >> 7, col = i & 127;
    const float v = ((row < 512) ? emb[i] : init_t[col]) * SCALE;
    const _Float16 h = (_Float16)v;
    e16hi[i] = h;
    e16lo[i] = (_Float16)(v - (float)h);
  }
  if (i == 0) { *gen = 0u; *cnt0 = 0u; *cnt1 = 0u; }
}

// Device-wide barrier (proven rounds 1-2).
__device__ __forceinline__ void gbar(unsigned* cnt0, unsigned* cnt1, unsigned* gen,
                                     unsigned q) {
  __syncthreads();
  if (threadIdx.x == 0) {
    unsigned* c = (q & 1u) ? cnt1 : cnt0;
    __threadfence();
    unsigned arrived = __hip_atomic_fetch_add(c, 1u, __ATOMIC_ACQ_REL,
                                              __HIP_MEMORY_SCOPE_AGENT);
    if (arrived == NBLK - 1u) {
      __hip_atomic_store(c, 0u, __ATOMIC_RELAXED, __HIP_MEMORY_SCOPE_AGENT);
      __hip_atomic_store(gen, q + 1u, __ATOMIC_RELEASE, __HIP_MEMORY_SCOPE_AGENT);
    } else {
      while (__hip_atomic_load(gen, __ATOMIC_ACQUIRE, __HIP_MEMORY_SCOPE_AGENT) < q + 1u) {
        __builtin_amdgcn_s_sleep(1);
      }
    }
  }
  __syncthreads();
}

__device__ __forceinline__ float sigm(float x) { return 1.f / (1.f + expf(-x)); }

// fp32[8] -> scaled f16 hi/lo split
__device__ __forceinline__ void cvt8(const float* v, f16x8& hi, f16x8& lo) {
  #pragma unroll
  for (int j = 0; j < 8; ++j) {
    const float s = v[j] * SCALE;
    const _Float16 h = (_Float16)s;
    hi[j] = h;
    lo[j] = (_Float16)(s - (float)h);
  }
}

__global__ __launch_bounds__(NTHR, 2) void decode_kernel(
    const float* __restrict__ enc, const int* __restrict__ seq_lens,
    const float* __restrict__ W_ih, const float* __restrict__ W_hh,
    const float* __restrict__ b_ih, const float* __restrict__ b_hh,
    const float* __restrict__ W_lin, const float* __restrict__ b_lin,
    float* __restrict__ out, float* __restrict__ hbuf,
    _Float16* __restrict__ h16hi, _Float16* __restrict__ h16lo,
    const _Float16* __restrict__ e16hi, const _Float16* __restrict__ e16lo,
    unsigned long long* __restrict__ amax,
    unsigned* gen, unsigned* cnt0, unsigned* cnt1) {

  // LDS: per-wave MFMA partials gp[8 waves][16 m][64 b pad 66] + small buffers
  __shared__ float gp[8 * 16 * 66];   // 33792 B
  __shared__ int   idxbuf[64];
  __shared__ float lstash[136];

  const int tid  = threadIdx.x;
  const int lane = tid & 63;
  const int wv   = tid >> 6;          // 0..7
  const int bid  = blockIdx.x;
  const int l15  = lane & 15;
  const int lq   = lane >> 4;         // quad 0..3

  // ---- MFMA identity: block owns 16 gate-rows (m = g*4+mi <-> r = g*H + bid*4+mi)
  const int am   = l15;               // A-fragment row for this lane
  const int arow = (am >> 2) * H + bid * 4 + (am & 3);
  // wave k-slice: waves 0..3 own 9 k-tiles, 4..7 own 8 (68 total, K=2176)
  const int ktbase = (wv < 4) ? wv * 9 : 36 + (wv - 4) * 8;
  const int ntk    = (wv < 4) ? 9 : 8;

  // ---- prologue: W -> scaled f16 hi/lo A-fragments, resident all 512 steps ----
  // A-frag lane layout (16x16x32): A[m=lane&15][k = quad*8 + j], j=0..7
  f16x8 ahi[9], alo[9];
  #pragma unroll
  for (int i = 0; i < 9; ++i) {
    if (i < ntk) {
      const int kg = (ktbase + i) * 32 + lq * 8;   // 0..2175, 8-aligned
      float wv8[8];
      const float* src;
      if (kg < 1024)       src = W_ih + (size_t)arow * (D + E) + kg;
      else if (kg < 2048)  src = W_hh + (size_t)arow * H + (kg - 1024);
      else                 src = W_ih + (size_t)arow * (D + E) + D + (kg - 2048);
      *(float4*)(wv8)     = *(const float4*)(src);
      *(float4*)(wv8 + 4) = *(const float4*)(src + 4);
      cvt8(wv8, ahi[i], alo[i]);
    } else {
      ahi[i] = (f16x8)(_Float16)0.f; alo[i] = (f16x8)(_Float16)0.f;
    }
  }

  // ---- cell-update identity: tid<256 owns (cmi, cb) ----
  const int cb  = tid & 63;
  const int cmi = tid >> 6;                        // valid when tid < 256
  const int csl = seq_lens[cb];
  float bias[4];
  if (tid < 256) {
    #pragma unroll
    for (int g = 0; g < 4; ++g) {
      const int r = g * H + bid * 4 + cmi;
      bias[g] = b_ih[r] + b_hh[r];
    }
  }
  const int sl_pre = (tid < 64) ? seq_lens[tid] : 0;

  // ---- phase B identity (round-2 structure, exact fp32) ----
  const int bq = bid >> 5, og = bid & 31;
  const int kp = lane & 7;
  const int pb_b  = bq * 8 + (lane >> 3);
  const int pb_sl = seq_lens[pb_b];
  const int o0 = og * 16 + wv * 2, o1 = o0 + 1;
  const float bl0 = b_lin[o0], bl1 = b_lin[o1];

  float c_reg = 0.f, h_reg = 0.f;

  if (tid < 64) idxbuf[tid] = -1;
  __syncthreads();

  for (int t = 0; t < T; ++t) {
    // ---------- A-pre: feedback index + amax slot reset ----------
    if (tid < 64) {
      if (t > 0 && (t - 1) < sl_pre) {
        unsigned long long p = __hip_atomic_load(
            &amax[((t - 1) & 1) * 64 + tid], __ATOMIC_RELAXED, __HIP_MEMORY_SCOPE_AGENT);
        idxbuf[tid] = 511 - (int)(unsigned)(p & 0xffffffffu);
      }
    } else if (tid < 128) {
      __hip_atomic_store(&amax[(t & 1) * 64 + (tid - 64)], 0ull,
                         __ATOMIC_RELAXED, __HIP_MEMORY_SCOPE_AGENT);
    }
    __syncthreads();

    // ---------- phase A: gates via MFMA, 3-product f16 hi/lo split ----------
    const int par0 = t & 1;
    f32x4 acc[4] = {{0.f,0.f,0.f,0.f},{0.f,0.f,0.f,0.f},
                    {0.f,0.f,0.f,0.f},{0.f,0.f,0.f,0.f}};
    #pragma unroll
    for (int nt = 0; nt < 4; ++nt) {
      const int bb = nt * 16 + l15;            // B-frag batch (column n)
      const int eb = idxbuf[bb];
      const size_t ebase = (size_t)((eb < 0) ? 512 : eb) * 128;
      const float*    xrow = enc + ((size_t)bb * T + t) * D;
      const _Float16* hhi  = h16hi + (size_t)par0 * (B * H) + (size_t)bb * H;
      const _Float16* hlo  = h16lo + (size_t)par0 * (B * H) + (size_t)bb * H;
      #pragma unroll
      for (int i = 0; i < 9; ++i) {
        if (i < ntk) {
          const int kt = ktbase + i;
          const int kg = kt * 32 + lq * 8;
          f16x8 bhi, blo;
          if (kt < 32) {                       // x region: fp32 -> on-the-fly split
            float xv[8];
            *(float4*)(xv)     = *(const float4*)(xrow + kg);
            *(float4*)(xv + 4) = *(const float4*)(xrow + kg + 4);
            cvt8(xv, bhi, blo);
          } else if (kt < 64) {                // h region: pre-split f16
            bhi = *(const f16x8*)(hhi + (kg - 1024));
            blo = *(const f16x8*)(hlo + (kg - 1024));
          } else {                             // emb region: pre-split f16 gather
            bhi = *(const f16x8*)(e16hi + ebase + (kg - 2048));
            blo = *(const f16x8*)(e16lo + ebase + (kg - 2048));
          }
          acc[nt] = __builtin_amdgcn_mfma_f32_16x16x32_f16(ahi[i], bhi, acc[nt], 0, 0, 0);
          acc[nt] = __builtin_amdgcn_mfma_f32_16x16x32_f16(alo[i], bhi, acc[nt], 0, 0, 0);
          acc[nt] = __builtin_amdgcn_mfma_f32_16x16x32_f16(ahi[i], blo, acc[nt], 0, 0, 0);
        }
      }
    }
    // C-layout: col b = nt*16 + (lane&15), row m = quad*4 + reg
    {
      const int prow = lq * 4;
      #pragma unroll
      for (int nt = 0; nt < 4; ++nt) {
        const int pb = nt * 16 + l15;
        #pragma unroll
        for (int r = 0; r < 4; ++r)
          gp[(wv * 16 + prow + r) * 66 + pb] = acc[nt][r];
      }
    }
    __syncthreads();

    // ---------- cell update: sum 8 wave-partials, LSTM math (fp32) ----------
    if (tid < 256) {
      float g4[4];
      #pragma unroll
      for (int g = 0; g < 4; ++g) {
        float s = 0.f;
        #pragma unroll
        for (int w = 0; w < 8; ++w) s += gp[(w * 16 + g * 4 + cmi) * 66 + cb];
        g4[g] = s * INV_SCALE2 + bias[g];
      }
      const float xi = sigm(g4[0]), xf = sigm(g4[1]);
      const float xg = tanhf(g4[2]), xo = sigm(g4[3]);
      const float cn = xf * c_reg + xi * xg;
      const float hn = xo * tanhf(cn);
      if (t < csl) { c_reg = cn; h_reg = hn; }
      const int par1 = (t + 1) & 1;
      const size_t hoff = (size_t)par1 * (B * H) + (size_t)cb * H + (bid * 4 + cmi);
      hbuf[hoff] = h_reg;
      const float hs = h_reg * SCALE;
      const _Float16 hh = (_Float16)hs;
      h16hi[hoff] = hh;
      h16lo[hoff] = (_Float16)(hs - (float)hh);
    }

    gbar(cnt0, cnt1, gen, 2u * (unsigned)t);  // h_t complete device-wide

    // ---------- phase B: exact fp32 logits + argmax (round-2 structure) ----------
    float f0 = 0.f, f1 = 0.f;
    const float* hr  = hbuf + (size_t)((t + 1) & 1) * (B * H) + (size_t)pb_b * H + kp * 4;
    const float* wl0 = W_lin + (size_t)o0 * H + kp * 4;
    const float* wl1 = W_lin + (size_t)o1 * H + kp * 4;
    #pragma unroll 4
    for (int j = 0; j < 32; ++j) {
      float4 h4 = *(const float4*)(hr + j * 32);
      float4 a4 = *(const float4*)(wl0 + j * 32);
      float4 c4 = *(const float4*)(wl1 + j * 32);
      f0 = fmaf(a4.x, h4.x, f0); f0 = fmaf(a4.y, h4.y, f0);
      f0 = fmaf(a4.z, h4.z, f0); f0 = fmaf(a4.w, h4.w, f0);
      f1 = fmaf(c4.x, h4.x, f1); f1 = fmaf(c4.y, h4.y, f1);
      f1 = fmaf(c4.z, h4.z, f1); f1 = fmaf(c4.w, h4.w, f1);
    }
    f0 += __shfl_xor(f0, 1, 64); f0 += __shfl_xor(f0, 2, 64); f0 += __shfl_xor(f0, 4, 64);
    f1 += __shfl_xor(f1, 1, 64); f1 += __shfl_xor(f1, 2, 64); f1 += __shfl_xor(f1, 4, 64);
    const float l0 = f0 + bl0, l1 = f1 + bl1;

    if (kp == 0) {
      const int boo = lane >> 3;
      lstash[boo * 17 + wv * 2]     = (t < pb_sl) ? l0 : 0.f;
      lstash[boo * 17 + wv * 2 + 1] = (t < pb_sl) ? l1 : 0.f;
      unsigned k0 = __float_as_uint(l0);
      k0 = (k0 & 0x80000000u) ? ~k0 : (k0 | 0x80000000u);
      unsigned k1 = __float_as_uint(l1);
      k1 = (k1 & 0x80000000u) ? ~k1 : (k1 | 0x80000000u);
      unsigned long long p0 = ((unsigned long long)k0 << 32) | (unsigned long long)(511 - o0);
      unsigned long long p1 = ((unsigned long long)k1 << 32) | (unsigned long long)(511 - o1);
      // reuse gp head as per-wave argmax scratch (safe: gp consumed pre-gbar)
      ((unsigned long long*)gp)[wv * 8 + boo] = (p0 > p1) ? p0 : p1;
    }
    __syncthreads();
    if (tid < 8) {
      unsigned long long m = ((unsigned long long*)gp)[tid];
      #pragma unroll
      for (int w = 1; w < 8; ++w) {
        unsigned long long v = ((unsigned long long*)gp)[w * 8 + tid];
        m = (v > m) ? v : m;
      }
      atomicMax(&amax[(t & 1) * 64 + bq * 8 + tid], m);
    }
    if (tid < 128) {
      const int bb = tid >> 4, oj = tid & 15;
      out[((size_t)(bq * 8 + bb) * T + t) * OO + og * 16 + oj] = lstash[bb * 17 + oj];
    }

    gbar(cnt0, cnt1, gen, 2u * (unsigned)t + 1u);  // logits/argmax complete
  }
}

extern "C" void kernel_launch(void* const* d_in, const int* in_sizes, int n_in,
                              void* d_out, int out_size, void* d_ws, size_t ws_size,
                              hipStream_t stream) {
  (void)in_sizes; (void)n_in; (void)out_size; (void)ws_size;
  const float* enc    = (const float*)d_in[0];
  const int*   slen   = (const int*)d_in[1];
  const float* W_ih   = (const float*)d_in[2];
  const float* W_hh   = (const float*)d_in[3];
  const float* b_ih   = (const float*)d_in[4];
  const float* b_hh   = (const float*)d_in[5];
  const float* W_lin  = (const float*)d_in[6];
  const float* b_lin  = (const float*)d_in[7];
  const float* emb    = (const float*)d_in[8];
  const float* init_t = (const float*)d_in[9];
  float* out = (float*)d_out;

  char* ws = (char*)d_ws;
  float*     hbuf  = (float*)(ws + WS_HBUF);
  _Float16*  h16hi = (_Float16*)(ws + WS_H16HI);
  _Float16*  h16lo = (_Float16*)(ws + WS_H16LO);
  _Float16*  e16hi = (_Float16*)(ws + WS_E16HI);
  _Float16*  e16lo = (_Float16*)(ws + WS_E16LO);
  unsigned long long* amax = (unsigned long long*)(ws + WS_AMAX);
  unsigned* gen  = (unsigned*)(ws + WS_GEN);
  unsigned* cnt0 = (unsigned*)(ws + WS_CNT0);
  unsigned* cnt1 = (unsigned*)(ws + WS_CNT1);

  hipLaunchKernelGGL(init_kernel, dim3(512), dim3(256), 0, stream,
                     hbuf, h16hi, h16lo, e16hi, e16lo, emb, init_t,
                     gen, cnt0, cnt1);
  hipLaunchKernelGGL(decode_kernel, dim3(NBLK), dim3(NTHR), 0, stream,
                     enc, slen, W_ih, W_hh, b_ih, b_hh, W_lin, b_lin,
                     out, hbuf, h16hi, h16lo, e16hi, e16lo, amax,
                     gen, cnt0, cnt1);
}